// Round 1
// baseline (410.486 us; speedup 1.0000x reference)
//
#include <hip/hip_runtime.h>

// Problem shape (fixed by reference setup_inputs):
//   inputs, running_mem: [B=32, H=112, W=112, C=128] f32, NHWC
//   out:                 [B=32, HO=56, WO=56, C=128] f32
//
// Analytic fusion of the reference:
//   mem = running_mem + inputs
//   per 2x2 window: pick position of (first) max of mem (row-major order);
//   out = max(inputs[that position], 0.0f)   (other window entries are 0 after masking)

#define B_  32
#define H_  112
#define W_  112
#define C_  128
#define HO_ 56
#define WO_ 56
#define C4_ (C_ / 4)   // 32 float4 groups per channel line

__device__ __forceinline__ float sel_relu(float i0, float i1, float i2, float i3,
                                          float m0, float m1, float m2, float m3) {
    // first-max (strict >) tie-break, row-major window order: (0,0),(0,1),(1,0),(1,1)
    float best = m0, sel = i0;
    if (m1 > best) { best = m1; sel = i1; }
    if (m2 > best) { best = m2; sel = i2; }
    if (m3 > best) { best = m3; sel = i3; }
    return fmaxf(sel, 0.0f);
}

__global__ __launch_bounds__(256) void spiking_maxpool_kernel(
        const float4* __restrict__ in,   // inputs
        const float4* __restrict__ rm,   // running_mem
        float4* __restrict__ out,
        int n4out) {
    const int stride = gridDim.x * blockDim.x;
    for (int i = blockIdx.x * blockDim.x + threadIdx.x; i < n4out; i += stride) {
        // i = ((b*HO + ho)*WO + wo)*C4 + c4  — identical to output float4 index
        int c4   = i & (C4_ - 1);
        int rest = i >> 5;                 // / C4_
        int wo   = rest % WO_;
        rest    /= WO_;
        int ho   = rest % HO_;
        int b    = rest / HO_;

        const int h0 = ho * 2;
        const int w0 = wo * 2;
        // base index in float4 units: ((b*H + h)*W + w)*C4 + c4
        const int base00 = ((b * H_ + h0) * W_ + w0) * C4_ + c4;
        const int base01 = base00 + C4_;         // (h0, w0+1)
        const int base10 = base00 + W_ * C4_;    // (h0+1, w0)
        const int base11 = base10 + C4_;         // (h0+1, w0+1)

        // 8 coalesced 16B loads per thread (512B per 32-lane group per position)
        const float4 i00 = in[base00];
        const float4 i01 = in[base01];
        const float4 i10 = in[base10];
        const float4 i11 = in[base11];
        const float4 r00 = rm[base00];
        const float4 r01 = rm[base01];
        const float4 r10 = rm[base10];
        const float4 r11 = rm[base11];

        float4 o;
        o.x = sel_relu(i00.x, i01.x, i10.x, i11.x,
                       r00.x + i00.x, r01.x + i01.x, r10.x + i10.x, r11.x + i11.x);
        o.y = sel_relu(i00.y, i01.y, i10.y, i11.y,
                       r00.y + i00.y, r01.y + i01.y, r10.y + i10.y, r11.y + i11.y);
        o.z = sel_relu(i00.z, i01.z, i10.z, i11.z,
                       r00.z + i00.z, r01.z + i01.z, r10.z + i10.z, r11.z + i11.z);
        o.w = sel_relu(i00.w, i01.w, i10.w, i11.w,
                       r00.w + i00.w, r01.w + i01.w, r10.w + i10.w, r11.w + i11.w);
        out[i] = o;
    }
}

extern "C" void kernel_launch(void* const* d_in, const int* in_sizes, int n_in,
                              void* d_out, int out_size, void* d_ws, size_t ws_size,
                              hipStream_t stream) {
    const float4* in = (const float4*)d_in[0];   // inputs
    const float4* rm = (const float4*)d_in[1];   // running_mem
    float4* out = (float4*)d_out;

    const int n4out = B_ * HO_ * WO_ * C4_;      // 3,211,264
    const int block = 256;
    int grid = (n4out + block - 1) / block;
    if (grid > 2048) grid = 2048;                // grid-stride, ~8 blocks/CU cap

    spiking_maxpool_kernel<<<grid, block, 0, stream>>>(in, rm, out, n4out);
}

// Round 4
// 408.819 us; speedup vs baseline: 1.0041x; 1.0041x over previous
//
#include <hip/hip_runtime.h>

// Shape (fixed): inputs, running_mem: [B=32, H=112, W=112, C=128] f32 NHWC
//                out:                 [B=32, HO=56, WO=56, C=128] f32
//
// Analytic fusion of the reference:
//   mem = running_mem + inputs
//   per 2x2 window: position of first max of mem (row-major);
//   out = max(inputs[that position], 0.0f)

#define B_  32
#define H_  112
#define W_  112
#define C_  128
#define HO_ 56
#define WO_ 56
#define C4_ 32              // 128/4 float4 groups per pixel
#define ROW_F4 (WO_ * C4_)  // 1792 float4 per output row
#define SEGS 7              // 1792 / 256 threads
#define IN_ROW_F4 (W_ * C4_) // 3584 float4 per input row

typedef float vfloat4 __attribute__((ext_vector_type(4)));  // native clang vector (builtin-compatible)

__device__ __forceinline__ float sel_relu(float i0, float i1, float i2, float i3,
                                          float m0, float m1, float m2, float m3) {
    // first-max (strict >) tie-break, row-major window order: (0,0),(0,1),(1,0),(1,1)
    float best = m0, sel = i0;
    if (m1 > best) { best = m1; sel = i1; }
    if (m2 > best) { best = m2; sel = i2; }
    if (m3 > best) { best = m3; sel = i3; }
    return fmaxf(sel, 0.0f);
}

__global__ __launch_bounds__(256) void spiking_maxpool_kernel(
        const float4* __restrict__ in,   // inputs
        const float4* __restrict__ rm,   // running_mem
        float4* __restrict__ out) {
    // block -> (output row, 256-wide segment); all scalar (wave-uniform)
    const int blk = blockIdx.x;
    const int row = blk / SEGS;                 // b*HO + ho
    const int seg = blk - row * SEGS;
    // per-lane: position within the output row (shifts/ands only)
    const int t  = (seg << 8) + threadIdx.x;    // 0..1791
    const int wo = t >> 5;
    const int c4 = t & 31;
    const int b  = row / HO_;                   // scalar
    const int ho = row - b * HO_;               // scalar

    // input base (float4 units): ((b*H + 2*ho)*W + 2*wo)*C4 + c4
    const int base00 = ((b * H_ + ho * 2) * W_ + wo * 2) * C4_ + c4;
    const int base01 = base00 + C4_;            // (h0, w0+1)
    const int base10 = base00 + IN_ROW_F4;      // (h0+1, w0)
    const int base11 = base10 + C4_;            // (h0+1, w0+1)

    // 8 independent 16B loads, issued immediately after a shift/and chain
    const float4 i00 = in[base00];
    const float4 i01 = in[base01];
    const float4 i10 = in[base10];
    const float4 i11 = in[base11];
    const float4 r00 = rm[base00];
    const float4 r01 = rm[base01];
    const float4 r10 = rm[base10];
    const float4 r11 = rm[base11];

    vfloat4 o;
    o.x = sel_relu(i00.x, i01.x, i10.x, i11.x,
                   r00.x + i00.x, r01.x + i01.x, r10.x + i10.x, r11.x + i11.x);
    o.y = sel_relu(i00.y, i01.y, i10.y, i11.y,
                   r00.y + i00.y, r01.y + i01.y, r10.y + i10.y, r11.y + i11.y);
    o.z = sel_relu(i00.z, i01.z, i10.z, i11.z,
                   r00.z + i00.z, r01.z + i01.z, r10.z + i10.z, r11.z + i11.z);
    o.w = sel_relu(i00.w, i01.w, i10.w, i11.w,
                   r00.w + i00.w, r01.w + i01.w, r10.w + i10.w, r11.w + i11.w);

    // write-once output: nontemporal store keeps L2/L3 lines free for reads
    __builtin_nontemporal_store(o, (vfloat4*)&out[row * ROW_F4 + t]);
}

extern "C" void kernel_launch(void* const* d_in, const int* in_sizes, int n_in,
                              void* d_out, int out_size, void* d_ws, size_t ws_size,
                              hipStream_t stream) {
    const float4* in = (const float4*)d_in[0];   // inputs
    const float4* rm = (const float4*)d_in[1];   // running_mem
    float4* out = (float4*)d_out;

    const int grid = B_ * HO_ * SEGS;            // 32*56*7 = 12544 blocks
    spiking_maxpool_kernel<<<grid, 256, 0, stream>>>(in, rm, out);
}